// Round 16
// baseline (932.313 us; speedup 1.0000x reference)
//
#include <hip/hip_runtime.h>
#include <math.h>

// ---------------------------------------------------------------------------
// Round 16: r15 + single-barrier K-loop. Old: STAGE;vmcnt;bar;read;lgkm0;bar2;
// MFMA (2 barriers/tile). New: vmcnt(0);bar;STAGE(next);read;MFMA (1 barrier).
// Write-after-read safe: staged buffer's readers drained (MFMA consumed all
// reads) before the barrier. Compiler now fine-interleaves ds_read<->MFMA.
// ---------------------------------------------------------------------------

namespace {
constexpr int S_   = 4096;
constexpr int D_   = 1536;
constexpr int H_   = 12;
constexpr int L_   = 512;
constexpr int TOPK = 8;
constexpr int FF_  = 8960;
constexpr float EPS_   = 1e-6f;
constexpr float SCALE_ = 0.08838834764831845f;   // 128^-0.5
}

typedef __attribute__((ext_vector_type(8))) short short8;
typedef __attribute__((ext_vector_type(4))) float f32x4;

#define AS_GLOBAL __attribute__((address_space(1)))
#define AS_LDS    __attribute__((address_space(3)))

__device__ __forceinline__ short f2bf(float x) {
    uint32_t u = __float_as_uint(x);
    uint32_t r = (u + 0x7FFFu + ((u >> 16) & 1u)) >> 16;
    return (short)r;
}
__device__ __forceinline__ float bf2f(short s) {
    return __uint_as_float(((uint32_t)(uint16_t)s) << 16);
}
__device__ __forceinline__ float gelu_tanh(float x) {
    const float t = tanhf(0.7978845608028654f * (x + 0.044715f * x * x * x));
    return 0.5f * x * (1.f + t);
}

// ---------------------------- reductions -----------------------------------
__device__ __forceinline__ float block_sum_256(float v, float* red) {
#pragma unroll
    for (int off = 32; off > 0; off >>= 1) v += __shfl_down(v, off, 64);
    const int lane = threadIdx.x & 63, w = threadIdx.x >> 6;
    if (lane == 0) red[w] = v;
    __syncthreads();
    v = red[0] + red[1] + red[2] + red[3];
    __syncthreads();
    return v;
}

// ====================== 128x64x64 4-wave MFMA GEMM =========================
// C(M,N) = A(M,K) @ Bt(N,K)^T. 256 thr, 4 waves; per-wave 64x32 out,
// acc[4][2]. LDS 48KB dbuf -> 3 blocks/CU. Single barrier per K-tile:
//   iter t: vmcnt(0) [tile t landed; issued ~1 iter ago] ; barrier ;
//           STAGE(t+1 -> buf^1) ; ds_read buf ; MFMA (compiler-interleaved).
// Swizzle u^(row&7) both sides, XCD swizzle + 4-row M-stripe raster.
// EPI: 0 C=acc+bias(f32) ; 2 Cb=bf16(gelu(acc+bias)) ;
//      4 QKVG (N=6144): Cb[seg*SD + row*1536 + cl] = bf16(acc+bias)
//      6 C = Rres + (acc+bias)*gate[col] ; 7 C += acc + bias
template <int EPI>
__global__ __launch_bounds__(256, 3) void gemm16(
    const short* __restrict__ A, const short* __restrict__ Bt,
    const float* __restrict__ bias, float* __restrict__ C,
    short* __restrict__ Cb, int M, int N, int K,
    const float* __restrict__ Rres, const float* __restrict__ gate)
{
    __shared__ __align__(16) short As[2][128 * 64];
    __shared__ __align__(16) short Bs[2][64 * 64];
    const int tid = threadIdx.x;
    const int wid = tid >> 6, lane = tid & 63;
    const int wm = wid >> 1, wn = wid & 1;
    const int g16 = lane >> 4, l15 = lane & 15;

    // bijective XCD swizzle + 4-row M-stripe raster
    const int gx = gridDim.x;
    const int nwg = gx * gridDim.y;
    const int bid = blockIdx.y * gx + blockIdx.x;
    const int qq = nwg >> 3, r8 = nwg & 7;
    const int xcd = bid & 7, lid = bid >> 3;
    const int swz = ((xcd < r8) ? xcd * (qq + 1) : r8 * (qq + 1) + (xcd - r8) * qq) + lid;
    const int stripe = swz / (4 * gx);
    const int within = swz - stripe * (4 * gx);
    const int m0 = (stripe * 4 + (within & 3)) * 128;
    const int n0 = (within >> 2) * 64;

    f32x4 acc[4][2];
#pragma unroll
    for (int i = 0; i < 4; i++)
#pragma unroll
        for (int j = 0; j < 2; j++) acc[i][j] = (f32x4){0.f, 0.f, 0.f, 0.f};

    int ar[4], au[4], br[2], bu[2];
#pragma unroll
    for (int i = 0; i < 4; i++) {
        const int c = tid + 256 * i;
        ar[i] = c >> 3;
        au[i] = (c & 7) ^ (ar[i] & 7);
    }
#pragma unroll
    for (int i = 0; i < 2; i++) {
        const int c = tid + 256 * i;
        br[i] = c >> 3;
        bu[i] = (c & 7) ^ (br[i] & 7);
    }

    auto STAGE = [&](int buf, int kt) {
#pragma unroll
        for (int i = 0; i < 4; i++)
            __builtin_amdgcn_global_load_lds(
                (const AS_GLOBAL short*)(A + (size_t)(m0 + ar[i]) * K + kt + au[i] * 8),
                (AS_LDS short*)(&As[buf][(tid + 256 * i) * 8]), 16, 0, 0);
#pragma unroll
        for (int i = 0; i < 2; i++)
            __builtin_amdgcn_global_load_lds(
                (const AS_GLOBAL short*)(Bt + (size_t)(n0 + br[i]) * K + kt + bu[i] * 8),
                (AS_LDS short*)(&Bs[buf][(tid + 256 * i) * 8]), 16, 0, 0);
    };

    const int nk = K >> 6;
    STAGE(0, 0);

    int cur = 0;
    for (int t = 0; t < nk; ++t) {
        asm volatile("s_waitcnt vmcnt(0)" ::: "memory");   // tile t landed
        __builtin_amdgcn_s_barrier();                       // all DMAs visible
        __builtin_amdgcn_sched_barrier(0);

        if (t + 1 < nk) STAGE(cur ^ 1, (t + 1) << 6);       // overlaps compute

        short8 a[4][2], b[2][2];
#pragma unroll
        for (int mi = 0; mi < 4; mi++) {
            const int row = wm * 64 + mi * 16 + l15;
#pragma unroll
            for (int kk = 0; kk < 2; kk++) {
                const int u = (kk * 4 + g16) ^ (row & 7);
                a[mi][kk] = *(const short8*)(As[cur] + row * 64 + u * 8);
            }
        }
#pragma unroll
        for (int ni = 0; ni < 2; ni++) {
            const int row = wn * 32 + ni * 16 + l15;
#pragma unroll
            for (int kk = 0; kk < 2; kk++) {
                const int u = (kk * 4 + g16) ^ (row & 7);
                b[ni][kk] = *(const short8*)(Bs[cur] + row * 64 + u * 8);
            }
        }

        __builtin_amdgcn_s_setprio(1);
#pragma unroll
        for (int mi = 0; mi < 4; mi++)
#pragma unroll
            for (int ni = 0; ni < 2; ni++)
#pragma unroll
                for (int kk = 0; kk < 2; kk++)
                    acc[mi][ni] = __builtin_amdgcn_mfma_f32_16x16x32_bf16(
                        a[mi][kk], b[ni][kk], acc[mi][ni], 0, 0, 0);
        __builtin_amdgcn_s_setprio(0);

        cur ^= 1;
    }

    const size_t SD = (size_t)S_ * D_;
#pragma unroll
    for (int mi = 0; mi < 4; mi++) {
#pragma unroll
        for (int ni = 0; ni < 2; ni++) {
            const int col = n0 + wn * 32 + ni * 16 + l15;
            const float bv = bias[col];
#pragma unroll
            for (int rr = 0; rr < 4; rr++) {
                const int row = m0 + wm * 64 + mi * 16 + g16 * 4 + rr;
                const float v = acc[mi][ni][rr];
                if (EPI == 4) {
                    const int seg = col / 1536, cl = col - seg * 1536;
                    Cb[(size_t)seg * SD + (size_t)row * 1536 + cl] = f2bf(v + bv);
                } else {
                    const size_t o = (size_t)row * N + col;
                    if (EPI == 0) C[o] = v + bv;
                    else if (EPI == 2) Cb[o] = f2bf(gelu_tanh(v + bv));
                    else if (EPI == 6) C[o] = Rres[o] + (v + bv) * gate[col];
                    else if (EPI == 7) C[o] += v + bv;
                }
            }
        }
    }
}

// ---------------------- weight transpose / convert -------------------------
__global__ __launch_bounds__(256) void transpose_w(
    const float* __restrict__ W, short* __restrict__ Th, int Kd, int Nd)
{
    __shared__ float tile[64][65];
    const int k0 = blockIdx.y * 64, n0 = blockIdx.x * 64;
    for (int f = threadIdx.x; f < 1024; f += 256) {
        const int rr = f >> 4, c4 = (f & 15) * 4;
        const float4 v = *(const float4*)(W + (size_t)(k0 + rr) * Nd + n0 + c4);
        tile[rr][c4 + 0] = v.x; tile[rr][c4 + 1] = v.y;
        tile[rr][c4 + 2] = v.z; tile[rr][c4 + 3] = v.w;
    }
    __syncthreads();
    for (int f = threadIdx.x; f < 1024; f += 256) {
        const int nn = f >> 4, k4 = (f & 15) * 4;
        short4 hv;
        hv.x = f2bf(tile[k4 + 0][nn]); hv.y = f2bf(tile[k4 + 1][nn]);
        hv.z = f2bf(tile[k4 + 2][nn]); hv.w = f2bf(tile[k4 + 3][nn]);
        *(short4*)(Th + (size_t)(n0 + nn) * Kd + k0 + k4) = hv;
    }
}

__global__ void cvt_bf16_kernel(const float* __restrict__ x, short* __restrict__ y, int n4)
{
    const int i = blockIdx.x * 256 + threadIdx.x;
    if (i >= n4) return;
    const float4 v = *(const float4*)(x + (size_t)i * 4);
    short4 o; o.x = f2bf(v.x); o.y = f2bf(v.y); o.z = f2bf(v.z); o.w = f2bf(v.w);
    *(short4*)(y + (size_t)i * 4) = o;
}

__global__ void fill_bcat(const float* __restrict__ bq, const float* __restrict__ bk,
                          const float* __restrict__ bv, const float* __restrict__ bg,
                          float* __restrict__ bcat)
{
    const int i = blockIdx.x * 256 + threadIdx.x;
    if (i >= 6144) return;
    const int seg = i / 1536, c = i - seg * 1536;
    const float* src = (seg == 0) ? bq : (seg == 1) ? bk : (seg == 2) ? bv : bg;
    bcat[i] = src[c];
}

// --------------------------- LayerNorm (bf16 out) ---------------------------
template <int ADD1>
__global__ __launch_bounds__(256) void ln_bf16(
    const float* __restrict__ x, short* __restrict__ hi,
    const float* __restrict__ g, const float* __restrict__ b)
{
    __shared__ float red[4];
    const size_t s = blockIdx.x;
    const float* xr = x + s * D_;
    float v[6];
    float sm = 0.f;
#pragma unroll
    for (int i = 0; i < 6; i++) { v[i] = xr[threadIdx.x + 256 * i]; sm += v[i]; }
    sm = block_sum_256(sm, red);
    const float mean = sm * (1.f / D_);
    float vs = 0.f;
#pragma unroll
    for (int i = 0; i < 6; i++) { const float d = v[i] - mean; vs += d * d; }
    vs = block_sum_256(vs, red);
    const float rs = rsqrtf(vs * (1.f / D_) + EPS_);
#pragma unroll
    for (int i = 0; i < 6; i++) {
        const int d = threadIdx.x + 256 * i;
        hi[s * D_ + d] = f2bf((v[i] - mean) * rs * (g[d] + (float)ADD1) + b[d]);
    }
}

__global__ __launch_bounds__(256) void rms_kernel(float* __restrict__ x,
                                                  const float* __restrict__ w)
{
    __shared__ float red[4];
    const size_t s = blockIdx.x;
    float* xr = x + s * D_;
    float v[6];
    float ss = 0.f;
#pragma unroll
    for (int i = 0; i < 6; i++) { v[i] = xr[threadIdx.x + 256 * i]; ss += v[i] * v[i]; }
    ss = block_sum_256(ss, red);
    const float rs = rsqrtf(ss * (1.f / D_) + EPS_);
#pragma unroll
    for (int i = 0; i < 6; i++) {
        const int d = threadIdx.x + 256 * i;
        xr[d] = v[i] * rs * w[d];
    }
}

// ------------- fused RMS + RoPE for bf16 Q and K (in-place) ----------------
__global__ __launch_bounds__(256) void rmsrope_qk_bf16(
    short* __restrict__ Q, short* __restrict__ K,
    const float* __restrict__ nqw, const float* __restrict__ nkw,
    const float* __restrict__ cosT, const float* __restrict__ sinT)
{
    __shared__ float red[4];
    const size_t s = blockIdx.x;
    const int tid = threadIdx.x;

#pragma unroll
    for (int m = 0; m < 2; m++) {
        short* X = m ? K : Q;
        const float* w = m ? nkw : nqw;
        float v1[3], v2[3];
        float ss = 0.f;
#pragma unroll
        for (int j = 0; j < 3; j++) {
            const short2 p2 = *(const short2*)(X + s * D_ + 2 * (tid + 256 * j));
            v1[j] = bf2f(p2.x); v2[j] = bf2f(p2.y);
            ss += v1[j] * v1[j] + v2[j] * v2[j];
        }
        ss = block_sum_256(ss, red);
        const float rs = rsqrtf(ss * (1.f / D_) + EPS_);
#pragma unroll
        for (int j = 0; j < 3; j++) {
            const int p = tid + 256 * j;
            const int i = p & 63;
            const float c = cosT[s * 64 + i], sn = sinT[s * 64 + i];
            const float x1 = v1[j] * rs * w[2 * p];
            const float x2 = v2[j] * rs * w[2 * p + 1];
            short2 o;
            o.x = f2bf(x1 * c - x2 * sn);
            o.y = f2bf(x2 * c + x1 * sn);
            *(short2*)(X + s * D_ + 2 * p) = o;
        }
    }
}

// --------------------------- elementwise -----------------------------------
__global__ void add_kernel(const float* __restrict__ a, const float* __restrict__ b,
                           float* __restrict__ o, int n)
{
    const int i = blockIdx.x * 256 + threadIdx.x;
    if (i < n) o[i] = a[i] + b[i];
}

// ------------------------- VSA coarse path ---------------------------------
__global__ __launch_bounds__(128) void blockmean_bf16(const short* __restrict__ q,
                                                      float* __restrict__ qc)
{
    const int hb = blockIdx.x;
    const int h = hb >> 6, j = hb & 63;
    const int d = threadIdx.x;
    float sum = 0.f;
    for (int t = 0; t < 64; t++)
        sum += bf2f(q[(size_t)(j * 64 + t) * D_ + h * 128 + d]);
    qc[(size_t)hb * 128 + d] = sum * (1.f / 64.f);
}

__global__ __launch_bounds__(64) void coarse_kernel(
    const float* __restrict__ qc, const float* __restrict__ kc,
    const float* __restrict__ vc, float* __restrict__ oc, int* __restrict__ idxout)
{
    const int hb = blockIdx.x;
    const int h = hb >> 6, i = hb & 63;
    const int lane = threadIdx.x;
    __shared__ float p[64];

    const float* qv = qc + (size_t)hb * 128;
    const float* kv = kc + (size_t)((h << 6) + lane) * 128;
    float sc = 0.f;
    for (int d = 0; d < 128; d++) sc = fmaf(qv[d], kv[d], sc);
    sc *= SCALE_;

    float mx = sc;
#pragma unroll
    for (int off = 32; off > 0; off >>= 1) mx = fmaxf(mx, __shfl_xor(mx, off, 64));
    const float e = expf(sc - mx);
    float sumv = e;
#pragma unroll
    for (int off = 32; off > 0; off >>= 1) sumv += __shfl_xor(sumv, off, 64);
    const float pv = e / sumv;
    p[lane] = pv;
    __syncthreads();

    float o0 = 0.f, o1 = 0.f;
    for (int j = 0; j < 64; j++) {
        const float pj = p[j];
        const float* vr = vc + (size_t)((h << 6) + j) * 128;
        o0 = fmaf(pj, vr[lane], o0);
        o1 = fmaf(pj, vr[lane + 64], o1);
    }
    oc[(size_t)hb * 128 + lane]      = o0;
    oc[(size_t)hb * 128 + lane + 64] = o1;

    float v = pv;
    for (int t = 0; t < TOPK; t++) {
        float bv = v; int bi = lane;
#pragma unroll
        for (int off = 32; off > 0; off >>= 1) {
            const float ov = __shfl_xor(bv, off, 64);
            const int   oi = __shfl_xor(bi, off, 64);
            if (ov > bv || (ov == bv && oi < bi)) { bv = ov; bi = oi; }
        }
        if (lane == 0) idxout[hb * TOPK + t] = bi;
        if (lane == bi) v = -1.f;
    }
}

// ---------------------- MFMA flash attention -------------------------------
// MODE 0: fine VSA — Q,K,V bf16 (Qb,Kb,Vb), epilogue += oc*g.
// MODE 1: cross-attn — Q,K,V f32 (Q_, CK_, CV_).
template <int MODE>
__global__ __launch_bounds__(256) void attn_mfma(
    const short* __restrict__ Qb, const short* __restrict__ Kb,
    const short* __restrict__ Vbb,
    const float* __restrict__ Qf, const float* __restrict__ Kf,
    const float* __restrict__ Vff,
    const short* __restrict__ Gb, const float* __restrict__ ocp,
    const int* __restrict__ idxp, short* __restrict__ Ob)
{
    const int hb = blockIdx.x, h = hb >> 6, ib = hb & 63;
    const int tid = threadIdx.x, wid = tid >> 6, lane = tid & 63;
    const int g16 = lane >> 4, l15 = lane & 15;

    __shared__ __align__(16) short Ks[64 * 128];
    __shared__ __align__(16) short Vst[128 * 64];
    __shared__ __align__(16) short Ps[64 * 80];
    __shared__ int sel[8];
    if (tid < 8) sel[tid] = (MODE == 0) ? idxp[hb * 8 + tid] : tid;

    short8 qa[4];
    if (MODE == 0) {
        const short* qrow = Qb + (size_t)(ib * 64 + wid * 16 + l15) * D_ + h * 128;
#pragma unroll
        for (int kk = 0; kk < 4; kk++)
            qa[kk] = *(const short8*)(qrow + kk * 32 + g16 * 8);
    } else {
        const float* qrow = Qf + (size_t)(ib * 64 + wid * 16 + l15) * D_ + h * 128;
#pragma unroll
        for (int kk = 0; kk < 4; kk++) {
            const float4 f0 = *(const float4*)(qrow + kk * 32 + g16 * 8);
            const float4 f1 = *(const float4*)(qrow + kk * 32 + g16 * 8 + 4);
            short8 v;
            v[0] = f2bf(f0.x); v[1] = f2bf(f0.y); v[2] = f2bf(f0.z); v[3] = f2bf(f0.w);
            v[4] = f2bf(f1.x); v[5] = f2bf(f1.y); v[6] = f2bf(f1.z); v[7] = f2bf(f1.w);
            qa[kk] = v;
        }
    }

    f32x4 o[8];
#pragma unroll
    for (int n2 = 0; n2 < 8; n2++) o[n2] = (f32x4){0.f, 0.f, 0.f, 0.f};
    float mrow[4] = {-3e38f, -3e38f, -3e38f, -3e38f};
    float lrow[4] = {0.f, 0.f, 0.f, 0.f};
    __syncthreads();

    for (int t = 0; t < 8; t++) {
        const int jb = sel[t];
#pragma unroll
        for (int it = 0; it < 4; it++) {
            const int c = tid + 256 * it;
            const int key = c >> 4, u16 = c & 15;
            const int byte = (key * 256 + u16 * 16) ^ ((key & 7) << 4);
            if (MODE == 0) {
                *(short8*)((char*)Ks + byte) =
                    *(const short8*)(Kb + (size_t)(jb * 64 + key) * D_ + h * 128 + u16 * 8);
            } else {
                const float* src = Kf + (size_t)(jb * 64 + key) * D_ + h * 128 + u16 * 8;
                const float4 f0 = *(const float4*)src;
                const float4 f1 = *(const float4*)(src + 4);
                short8 v;
                v[0] = f2bf(f0.x); v[1] = f2bf(f0.y); v[2] = f2bf(f0.z); v[3] = f2bf(f0.w);
                v[4] = f2bf(f1.x); v[5] = f2bf(f1.y); v[6] = f2bf(f1.z); v[7] = f2bf(f1.w);
                *(short8*)((char*)Ks + byte) = v;
            }
        }
#pragma unroll
        for (int it = 0; it < 4; it++) {
            const int c = tid + 256 * it;
            const int key = c & 63, d8 = (c >> 6) * 8;
            float vv[8];
            if (MODE == 0) {
                const short8 v = *(const short8*)(Vbb + (size_t)(jb * 64 + key) * D_ + h * 128 + d8);
#pragma unroll
                for (int j = 0; j < 8; j++) vv[j] = bf2f(v[j]);
            } else {
                const float* src = Vff + (size_t)(jb * 64 + key) * D_ + h * 128 + d8;
                const float4 f0 = *(const float4*)src;
                const float4 f1 = *(const float4*)(src + 4);
                vv[0] = f0.x; vv[1] = f0.y; vv[2] = f0.z; vv[3] = f0.w;
                vv[4] = f1.x; vv[5] = f1.y; vv[6] = f1.z; vv[7] = f1.w;
            }
#pragma unroll
            for (int j = 0; j < 8; j++) {
                const int dim = d8 + j;
                const int byte = (dim * 128 + key * 2) ^ ((dim & 7) << 4);
                *(short*)((char*)Vst + byte) = f2bf(vv[j]);
            }
        }
        __syncthreads();

        f32x4 s[4];
#pragma unroll
        for (int nt = 0; nt < 4; nt++) {
            f32x4 acc = (f32x4){0.f, 0.f, 0.f, 0.f};
            const int key = nt * 16 + l15;
#pragma unroll
            for (int kk = 0; kk < 4; kk++) {
                const int byte = (key * 256 + (kk * 32 + g16 * 8) * 2) ^ ((key & 7) << 4);
                const short8 b = *(const short8*)((char*)Ks + byte);
                acc = __builtin_amdgcn_mfma_f32_16x16x32_bf16(qa[kk], b, acc, 0, 0, 0);
            }
            s[nt] = acc;
        }
#pragma unroll
        for (int nt = 0; nt < 4; nt++)
#pragma unroll
            for (int rr = 0; rr < 4; rr++) s[nt][rr] *= SCALE_;

        float alpha[4];
#pragma unroll
        for (int rr = 0; rr < 4; rr++) {
            float v = fmaxf(fmaxf(s[0][rr], s[1][rr]), fmaxf(s[2][rr], s[3][rr]));
            v = fmaxf(v, __shfl_xor(v, 1, 64));
            v = fmaxf(v, __shfl_xor(v, 2, 64));
            v = fmaxf(v, __shfl_xor(v, 4, 64));
            v = fmaxf(v, __shfl_xor(v, 8, 64));
            const float mn = fmaxf(mrow[rr], v);
            alpha[rr] = expf(mrow[rr] - mn);
            mrow[rr] = mn;
        }
        float rs[4] = {0.f, 0.f, 0.f, 0.f};
#pragma unroll
        for (int nt = 0; nt < 4; nt++)
#pragma unroll
            for (int rr = 0; rr < 4; rr++) {
                const float p = expf(s[nt][rr] - mrow[rr]);
                s[nt][rr] = p;
                rs[rr] += p;
            }
#pragma unroll
        for (int rr = 0; rr < 4; rr++) {
            float v = rs[rr];
            v += __shfl_xor(v, 1, 64);
            v += __shfl_xor(v, 2, 64);
            v += __shfl_xor(v, 4, 64);
            v += __shfl_xor(v, 8, 64);
            lrow[rr] = lrow[rr] * alpha[rr] + v;
        }
#pragma unroll
        for (int n2 = 0; n2 < 8; n2++)
#pragma unroll
            for (int rr = 0; rr < 4; rr++) o[n2][rr] *= alpha[rr];

#pragma unroll
        for (int nt = 0; nt < 4; nt++)
#pragma unroll
            for (int rr = 0; rr < 4; rr++)
                Ps[(wid * 16 + g16 * 4 + rr) * 80 + nt * 16 + l15] = f2bf(s[nt][rr]);

#pragma unroll
        for (int kk2 = 0; kk2 < 2; kk2++) {
            const short8 pa = *(const short8*)(Ps + (wid * 16 + l15) * 80 + kk2 * 32 + g16 * 8);
#pragma unroll
            for (int n2 = 0; n2 < 8; n2++) {
                const int dim = n2 * 16 + l15;
                const int byte = (dim * 128 + (kk2 * 32 + g16 * 8) * 2) ^ ((dim & 7) << 4);
                const short8 vb = *(const short8*)((char*)Vst + byte);
                o[n2] = __builtin_amdgcn_mfma_f32_16x16x32_bf16(pa, vb, o[n2], 0, 0, 0);
            }
        }
        __syncthreads();
    }

#pragma unroll
    for (int n2 = 0; n2 < 8; n2++) {
        const int col = n2 * 16 + l15;
        const float ocv = (MODE == 0) ? ocp[(size_t)hb * 128 + col] : 0.f;
#pragma unroll
        for (int rr = 0; rr < 4; rr++) {
            const int row = ib * 64 + wid * 16 + g16 * 4 + rr;
            float val = o[n2][rr] / lrow[rr];
            if (MODE == 0)
                val += ocv * bf2f(Gb[(size_t)row * D_ + h * 128 + col]);
            Ob[(size_t)row * D_ + h * 128 + col] = f2bf(val);
        }
    }
}

// ---------------------------------------------------------------------------
extern "C" void kernel_launch(void* const* d_in, const int* in_sizes, int n_in,
                              void* d_out, int out_size, void* d_ws, size_t ws_size,
                              hipStream_t stream)
{
    const float* h_in = (const float*)d_in[0];
    const float* enc  = (const float*)d_in[1];
    const float* temb = (const float*)d_in[2];
    const float* cosT = (const float*)d_in[3];
    const float* sinT = (const float*)d_in[4];
    const float* sst  = (const float*)d_in[5];
    const float* Wq = (const float*)d_in[6];   const float* bq = (const float*)d_in[7];
    const float* Wk = (const float*)d_in[8];   const float* bk = (const float*)d_in[9];
    const float* Wv = (const float*)d_in[10];  const float* bv = (const float*)d_in[11];
    const float* Wg = (const float*)d_in[12];  const float* bg = (const float*)d_in[13];
    const float* Wo = (const float*)d_in[14];  const float* bo = (const float*)d_in[15];
    const float* nq_w  = (const float*)d_in[16];
    const float* nk_w  = (const float*)d_in[17];
    const float* ln1_w = (const float*)d_in[18];
    const float* ln1_b = (const float*)d_in[19];
    const float* cWq = (const float*)d_in[20]; const float* cbq = (const float*)d_in[21];
    const float* cWk = (const float*)d_in[22]; const float* cbk = (const float*)d_in[23];
    const float* cWv = (const float*)d_in[24]; const float* cbv = (const float*)d_in[25];
    const float* cWo = (const float*)d_in[26]; const float* cbo = (const float*)d_in[27];
    const float* cnq_w = (const float*)d_in[28];
    const float* cnk_w = (const float*)d_in[29];
    const float* W1 = (const float*)d_in[30];  const float* b1 = (const float*)d_in[31];
    const float* W2 = (const float*)d_in[32];  const float* b2 = (const float*)d_in[33];
    float* out = (float*)d_out;

    char* base = (char*)d_ws;
    size_t off = 0;
    auto alloc = [&](size_t bytes) {
        char* p = base + off;
        off += (bytes + 255) & ~(size_t)255;
        return p;
    };
    const size_t SD = (size_t)S_ * D_;
    float* e_   = (float*)alloc(6 * D_ * 4);
    float* Q_   = (float*)alloc(SD * 4);       // cq (cross path)
    float* K_   = (float*)alloc(SD * 4);       // resid1/resid2
    float* CK_  = (float*)alloc((size_t)L_ * D_ * 4);
    float* CV_  = (float*)alloc((size_t)L_ * D_ * 4);
    float* qc_  = (float*)alloc((size_t)H_ * 64 * 128 * 4);
    float* kc_  = (float*)alloc((size_t)H_ * 64 * 128 * 4);
    float* vc_  = (float*)alloc((size_t)H_ * 64 * 128 * 4);
    float* oc_  = (float*)alloc((size_t)H_ * 64 * 128 * 4);
    int*   idx_ = (int*)alloc((size_t)H_ * 64 * TOPK * 4);
    short* Nb   = (short*)alloc(SD * 2);       // live during W1 (norm3)
    // ---- FFC alias region: QKVGb .. Wgt (~83 MB, all dead by FFN) ----
    short* QKVGb = (short*)alloc(4 * SD * 2);  // q|k|v|g bf16, seg stride SD
    short* attn_b = (short*)alloc(SD * 2);
    short* enc_b  = (short*)alloc((size_t)L_ * D_ * 2);
    const size_t WDD = (size_t)D_ * D_;
    short* Wqt = (short*)alloc(WDD * 2);       // Wqt,Wkt,Wvt,Wgt contiguous
    short* Wkt = (short*)alloc(WDD * 2);
    short* Wvt = (short*)alloc(WDD * 2);
    short* Wgt = (short*)alloc(WDD * 2);
    // ---- end alias region ----
    short* Wot = (short*)alloc(WDD * 2);
    short* cWqt = (short*)alloc(WDD * 2); short* cWkt = (short*)alloc(WDD * 2);
    short* cWvt = (short*)alloc(WDD * 2); short* cWot = (short*)alloc(WDD * 2);
    short* W1t = (short*)alloc((size_t)D_ * FF_ * 2);
    short* W2t = (short*)alloc((size_t)D_ * FF_ * 2);
    float* bcat = (float*)alloc(6144 * 4);
    short* FFC = QKVGb;   // S x FF bf16 (73.4 MB) over dead region (~83 MB)
    short* Qb = QKVGb;
    short* Kb = QKVGb + SD;
    short* Vb = QKVGb + 2 * SD;
    short* Gb = QKVGb + 3 * SD;

    const dim3 b256(256);
    const dim3 gDD(D_ / 64, D_ / 64);
    const dim3 gN1536(D_ / 64, S_ / 128);      // 24 x 32 = 768 blocks

    add_kernel<<<dim3((6 * D_ + 255) / 256), b256, 0, stream>>>(sst, temb, e_, 6 * D_);
    ln_bf16<1><<<dim3(S_), b256, 0, stream>>>(h_in, Nb, e_ + D_, e_);
    fill_bcat<<<dim3(24), b256, 0, stream>>>(bq, bk, bv, bg, bcat);

    transpose_w<<<gDD, b256, 0, stream>>>(Wq, Wqt, D_, D_);
    transpose_w<<<gDD, b256, 0, stream>>>(Wk, Wkt, D_, D_);
    transpose_w<<<gDD, b256, 0, stream>>>(Wv, Wvt, D_, D_);
    transpose_w<<<gDD, b256, 0, stream>>>(Wg, Wgt, D_, D_);
    transpose_w<<<gDD, b256, 0, stream>>>(Wo, Wot, D_, D_);
    transpose_w<<<gDD, b256, 0, stream>>>(cWq, cWqt, D_, D_);
    transpose_w<<<gDD, b256, 0, stream>>>(cWk, cWkt, D_, D_);
    transpose_w<<<gDD, b256, 0, stream>>>(cWv, cWvt, D_, D_);
    transpose_w<<<gDD, b256, 0, stream>>>(cWo, cWot, D_, D_);
    transpose_w<<<dim3(FF_ / 64, D_ / 64), b256, 0, stream>>>(W1, W1t, D_, FF_);
    transpose_w<<<dim3(D_ / 64, FF_ / 64), b256, 0, stream>>>(W2, W2t, FF_, D_);
    cvt_bf16_kernel<<<dim3((L_ * D_ / 4 + 255) / 256), b256, 0, stream>>>(enc, enc_b, L_ * D_ / 4);

    // fused QKVG projection -> QKVGb (all bf16)
    gemm16<4><<<dim3(6144 / 64, S_ / 128), b256, 0, stream>>>(
        Nb, Wqt, bcat, nullptr, QKVGb, S_, 6144, D_, nullptr, nullptr);

    // fused rms + rope for q,k (bf16 in-place)
    rmsrope_qk_bf16<<<dim3(S_), b256, 0, stream>>>(Qb, Kb, nq_w, nk_w, cosT, sinT);

    blockmean_bf16<<<dim3(H_ * 64), dim3(128), 0, stream>>>(Qb, qc_);
    blockmean_bf16<<<dim3(H_ * 64), dim3(128), 0, stream>>>(Kb, kc_);
    blockmean_bf16<<<dim3(H_ * 64), dim3(128), 0, stream>>>(Vb, vc_);
    coarse_kernel<<<dim3(H_ * 64), dim3(64), 0, stream>>>(qc_, kc_, vc_, oc_, idx_);

    attn_mfma<0><<<dim3(H_ * 64), b256, 0, stream>>>(
        Qb, Kb, Vb, nullptr, nullptr, nullptr, Gb, oc_, idx_, attn_b);

    // Wo fused with resid-gate: K_ = h_in + (attn@Wo + bo) * gate
    gemm16<6><<<gN1536, b256, 0, stream>>>(attn_b, Wot, bo, K_, nullptr, S_, D_, D_,
                                           h_in, e_ + 2 * D_);

    ln_bf16<0><<<dim3(S_), b256, 0, stream>>>(K_, Nb, ln1_w, ln1_b);
    gemm16<0><<<gN1536, b256, 0, stream>>>(Nb, cWqt, cbq, Q_, nullptr, S_, D_, D_,
                                           nullptr, nullptr);
    rms_kernel<<<dim3(S_), b256, 0, stream>>>(Q_, cnq_w);

    const dim3 gLenc(D_ / 64, L_ / 128);
    gemm16<0><<<gLenc, b256, 0, stream>>>(enc_b, cWkt, cbk, CK_, nullptr, L_, D_, D_,
                                          nullptr, nullptr);
    rms_kernel<<<dim3(L_), b256, 0, stream>>>(CK_, cnk_w);
    gemm16<0><<<gLenc, b256, 0, stream>>>(enc_b, cWvt, cbv, CV_, nullptr, L_, D_, D_,
                                          nullptr, nullptr);

    attn_mfma<1><<<dim3(H_ * 64), b256, 0, stream>>>(
        nullptr, nullptr, nullptr, Q_, CK_, CV_, nullptr, nullptr, nullptr, attn_b);

    // cWo fused with residual: K_ += cout@cWo + cbo
    gemm16<7><<<gN1536, b256, 0, stream>>>(attn_b, cWot, cbo, K_, nullptr, S_, D_, D_,
                                           nullptr, nullptr);

    // norm3 -> Nb ; FFN: W1(gelu->FFC bf16) ; W2 fused with final resid-gate
    ln_bf16<1><<<dim3(S_), b256, 0, stream>>>(K_, Nb, e_ + 4 * D_, e_ + 3 * D_);
    gemm16<2><<<dim3(FF_ / 64, S_ / 128), b256, 0, stream>>>(
        Nb, W1t, b1, nullptr, FFC, S_, FF_, D_, nullptr, nullptr);
    gemm16<6><<<gN1536, b256, 0, stream>>>(FFC, W2t, b2, out, nullptr, S_, D_, FF_,
                                           K_, e_ + 5 * D_);
}

// Round 17
// 905.942 us; speedup vs baseline: 1.0291x; 1.0291x over previous
//
#include <hip/hip_runtime.h>
#include <math.h>

// ---------------------------------------------------------------------------
// Round 17: r16 + staging-address hoisting. STAGE sources are loop-carried
// pointers advanced by +64 elems/tile (2 VALU each) instead of per-tile
// recompute with runtime-K integer muls (~30 VALU/tile). r16 counters:
// VALUBusy 34% > MfmaUtil 21% -> address arithmetic is contending for issue.
// ---------------------------------------------------------------------------

namespace {
constexpr int S_   = 4096;
constexpr int D_   = 1536;
constexpr int H_   = 12;
constexpr int L_   = 512;
constexpr int TOPK = 8;
constexpr int FF_  = 8960;
constexpr float EPS_   = 1e-6f;
constexpr float SCALE_ = 0.08838834764831845f;   // 128^-0.5
}

typedef __attribute__((ext_vector_type(8))) short short8;
typedef __attribute__((ext_vector_type(4))) float f32x4;

#define AS_GLOBAL __attribute__((address_space(1)))
#define AS_LDS    __attribute__((address_space(3)))

__device__ __forceinline__ short f2bf(float x) {
    uint32_t u = __float_as_uint(x);
    uint32_t r = (u + 0x7FFFu + ((u >> 16) & 1u)) >> 16;
    return (short)r;
}
__device__ __forceinline__ float bf2f(short s) {
    return __uint_as_float(((uint32_t)(uint16_t)s) << 16);
}
__device__ __forceinline__ float gelu_tanh(float x) {
    const float t = tanhf(0.7978845608028654f * (x + 0.044715f * x * x * x));
    return 0.5f * x * (1.f + t);
}

// ---------------------------- reductions -----------------------------------
__device__ __forceinline__ float block_sum_256(float v, float* red) {
#pragma unroll
    for (int off = 32; off > 0; off >>= 1) v += __shfl_down(v, off, 64);
    const int lane = threadIdx.x & 63, w = threadIdx.x >> 6;
    if (lane == 0) red[w] = v;
    __syncthreads();
    v = red[0] + red[1] + red[2] + red[3];
    __syncthreads();
    return v;
}

// ====================== 128x64x64 4-wave MFMA GEMM =========================
// C(M,N) = A(M,K) @ Bt(N,K)^T. 256 thr, 4 waves; per-wave 64x32 out,
// acc[4][2]. LDS 48KB dbuf -> 3 blocks/CU. Single barrier per K-tile:
//   iter t: vmcnt(0); barrier; STAGE(t+1 -> buf^1); ds_read buf; MFMA.
// Staging sources = loop-carried pointers (+64/tile). Swizzle u^(row&7)
// both sides; XCD swizzle + 4-row M-stripe raster (Mt%4==0).
// EPI: 0 C=acc+bias(f32) ; 2 Cb=bf16(gelu(acc+bias)) ;
//      4 QKVG (N=6144): Cb[seg*SD + row*1536 + cl] = bf16(acc+bias)
//      6 C = Rres + (acc+bias)*gate[col] ; 7 C += acc + bias
template <int EPI>
__global__ __launch_bounds__(256, 3) void gemm17(
    const short* __restrict__ A, const short* __restrict__ Bt,
    const float* __restrict__ bias, float* __restrict__ C,
    short* __restrict__ Cb, int M, int N, int K,
    const float* __restrict__ Rres, const float* __restrict__ gate)
{
    __shared__ __align__(16) short As[2][128 * 64];
    __shared__ __align__(16) short Bs[2][64 * 64];
    const int tid = threadIdx.x;
    const int wid = tid >> 6, lane = tid & 63;
    const int wm = wid >> 1, wn = wid & 1;
    const int g16 = lane >> 4, l15 = lane & 15;

    // bijective XCD swizzle + 4-row M-stripe raster
    const int gx = gridDim.x;
    const int nwg = gx * gridDim.y;
    const int bid = blockIdx.y * gx + blockIdx.x;
    const int qq = nwg >> 3, r8 = nwg & 7;
    const int xcd = bid & 7, lid = bid >> 3;
    const int swz = ((xcd < r8) ? xcd * (qq + 1) : r8 * (qq + 1) + (xcd - r8) * qq) + lid;
    const int stripe = swz / (4 * gx);
    const int within = swz - stripe * (4 * gx);
    const int m0 = (stripe * 4 + (within & 3)) * 128;
    const int n0 = (within >> 2) * 64;

    f32x4 acc[4][2];
#pragma unroll
    for (int i = 0; i < 4; i++)
#pragma unroll
        for (int j = 0; j < 2; j++) acc[i][j] = (f32x4){0.f, 0.f, 0.f, 0.f};

    // loop-carried staging pointers (advance +64 elems per staged tile)
    const AS_GLOBAL short* ap[4];
    const AS_GLOBAL short* bp[2];
#pragma unroll
    for (int i = 0; i < 4; i++) {
        const int c = tid + 256 * i;
        const int row = c >> 3;
        const int u = (c & 7) ^ (row & 7);
        ap[i] = (const AS_GLOBAL short*)(A + (size_t)(m0 + row) * K + u * 8);
    }
#pragma unroll
    for (int i = 0; i < 2; i++) {
        const int c = tid + 256 * i;
        const int row = c >> 3;
        const int u = (c & 7) ^ (row & 7);
        bp[i] = (const AS_GLOBAL short*)(Bt + (size_t)(n0 + row) * K + u * 8);
    }

    auto STAGE = [&](int buf) {
#pragma unroll
        for (int i = 0; i < 4; i++) {
            __builtin_amdgcn_global_load_lds(ap[i],
                (AS_LDS short*)(&As[buf][(tid + 256 * i) * 8]), 16, 0, 0);
            ap[i] += 64;
        }
#pragma unroll
        for (int i = 0; i < 2; i++) {
            __builtin_amdgcn_global_load_lds(bp[i],
                (AS_LDS short*)(&Bs[buf][(tid + 256 * i) * 8]), 16, 0, 0);
            bp[i] += 64;
        }
    };

    const int nk = K >> 6;
    STAGE(0);

    int cur = 0;
    for (int t = 0; t < nk; ++t) {
        asm volatile("s_waitcnt vmcnt(0)" ::: "memory");   // tile t landed
        __builtin_amdgcn_s_barrier();                       // all DMAs visible
        __builtin_amdgcn_sched_barrier(0);

        if (t + 1 < nk) STAGE(cur ^ 1);                     // overlaps compute

        short8 a[4][2], b[2][2];
#pragma unroll
        for (int mi = 0; mi < 4; mi++) {
            const int row = wm * 64 + mi * 16 + l15;
#pragma unroll
            for (int kk = 0; kk < 2; kk++) {
                const int u = (kk * 4 + g16) ^ (row & 7);
                a[mi][kk] = *(const short8*)(As[cur] + row * 64 + u * 8);
            }
        }
#pragma unroll
        for (int ni = 0; ni < 2; ni++) {
            const int row = wn * 32 + ni * 16 + l15;
#pragma unroll
            for (int kk = 0; kk < 2; kk++) {
                const int u = (kk * 4 + g16) ^ (row & 7);
                b[ni][kk] = *(const short8*)(Bs[cur] + row * 64 + u * 8);
            }
        }

        __builtin_amdgcn_s_setprio(1);
#pragma unroll
        for (int mi = 0; mi < 4; mi++)
#pragma unroll
            for (int ni = 0; ni < 2; ni++)
#pragma unroll
                for (int kk = 0; kk < 2; kk++)
                    acc[mi][ni] = __builtin_amdgcn_mfma_f32_16x16x32_bf16(
                        a[mi][kk], b[ni][kk], acc[mi][ni], 0, 0, 0);
        __builtin_amdgcn_s_setprio(0);

        cur ^= 1;
    }

    const size_t SD = (size_t)S_ * D_;
#pragma unroll
    for (int mi = 0; mi < 4; mi++) {
#pragma unroll
        for (int ni = 0; ni < 2; ni++) {
            const int col = n0 + wn * 32 + ni * 16 + l15;
            const float bv = bias[col];
#pragma unroll
            for (int rr = 0; rr < 4; rr++) {
                const int row = m0 + wm * 64 + mi * 16 + g16 * 4 + rr;
                const float v = acc[mi][ni][rr];
                if (EPI == 4) {
                    const int seg = col / 1536, cl = col - seg * 1536;
                    Cb[(size_t)seg * SD + (size_t)row * 1536 + cl] = f2bf(v + bv);
                } else {
                    const size_t o = (size_t)row * N + col;
                    if (EPI == 0) C[o] = v + bv;
                    else if (EPI == 2) Cb[o] = f2bf(gelu_tanh(v + bv));
                    else if (EPI == 6) C[o] = Rres[o] + (v + bv) * gate[col];
                    else if (EPI == 7) C[o] += v + bv;
                }
            }
        }
    }
}

// ---------------------- weight transpose / convert -------------------------
__global__ __launch_bounds__(256) void transpose_w(
    const float* __restrict__ W, short* __restrict__ Th, int Kd, int Nd)
{
    __shared__ float tile[64][65];
    const int k0 = blockIdx.y * 64, n0 = blockIdx.x * 64;
    for (int f = threadIdx.x; f < 1024; f += 256) {
        const int rr = f >> 4, c4 = (f & 15) * 4;
        const float4 v = *(const float4*)(W + (size_t)(k0 + rr) * Nd + n0 + c4);
        tile[rr][c4 + 0] = v.x; tile[rr][c4 + 1] = v.y;
        tile[rr][c4 + 2] = v.z; tile[rr][c4 + 3] = v.w;
    }
    __syncthreads();
    for (int f = threadIdx.x; f < 1024; f += 256) {
        const int nn = f >> 4, k4 = (f & 15) * 4;
        short4 hv;
        hv.x = f2bf(tile[k4 + 0][nn]); hv.y = f2bf(tile[k4 + 1][nn]);
        hv.z = f2bf(tile[k4 + 2][nn]); hv.w = f2bf(tile[k4 + 3][nn]);
        *(short4*)(Th + (size_t)(n0 + nn) * Kd + k0 + k4) = hv;
    }
}

__global__ void cvt_bf16_kernel(const float* __restrict__ x, short* __restrict__ y, int n4)
{
    const int i = blockIdx.x * 256 + threadIdx.x;
    if (i >= n4) return;
    const float4 v = *(const float4*)(x + (size_t)i * 4);
    short4 o; o.x = f2bf(v.x); o.y = f2bf(v.y); o.z = f2bf(v.z); o.w = f2bf(v.w);
    *(short4*)(y + (size_t)i * 4) = o;
}

__global__ void fill_bcat(const float* __restrict__ bq, const float* __restrict__ bk,
                          const float* __restrict__ bv, const float* __restrict__ bg,
                          float* __restrict__ bcat)
{
    const int i = blockIdx.x * 256 + threadIdx.x;
    if (i >= 6144) return;
    const int seg = i / 1536, c = i - seg * 1536;
    const float* src = (seg == 0) ? bq : (seg == 1) ? bk : (seg == 2) ? bv : bg;
    bcat[i] = src[c];
}

// --------------------------- LayerNorm (bf16 out) ---------------------------
template <int ADD1>
__global__ __launch_bounds__(256) void ln_bf16(
    const float* __restrict__ x, short* __restrict__ hi,
    const float* __restrict__ g, const float* __restrict__ b)
{
    __shared__ float red[4];
    const size_t s = blockIdx.x;
    const float* xr = x + s * D_;
    float v[6];
    float sm = 0.f;
#pragma unroll
    for (int i = 0; i < 6; i++) { v[i] = xr[threadIdx.x + 256 * i]; sm += v[i]; }
    sm = block_sum_256(sm, red);
    const float mean = sm * (1.f / D_);
    float vs = 0.f;
#pragma unroll
    for (int i = 0; i < 6; i++) { const float d = v[i] - mean; vs += d * d; }
    vs = block_sum_256(vs, red);
    const float rs = rsqrtf(vs * (1.f / D_) + EPS_);
#pragma unroll
    for (int i = 0; i < 6; i++) {
        const int d = threadIdx.x + 256 * i;
        hi[s * D_ + d] = f2bf((v[i] - mean) * rs * (g[d] + (float)ADD1) + b[d]);
    }
}

__global__ __launch_bounds__(256) void rms_kernel(float* __restrict__ x,
                                                  const float* __restrict__ w)
{
    __shared__ float red[4];
    const size_t s = blockIdx.x;
    float* xr = x + s * D_;
    float v[6];
    float ss = 0.f;
#pragma unroll
    for (int i = 0; i < 6; i++) { v[i] = xr[threadIdx.x + 256 * i]; ss += v[i] * v[i]; }
    ss = block_sum_256(ss, red);
    const float rs = rsqrtf(ss * (1.f / D_) + EPS_);
#pragma unroll
    for (int i = 0; i < 6; i++) {
        const int d = threadIdx.x + 256 * i;
        xr[d] = v[i] * rs * w[d];
    }
}

// ------------- fused RMS + RoPE for bf16 Q and K (in-place) ----------------
__global__ __launch_bounds__(256) void rmsrope_qk_bf16(
    short* __restrict__ Q, short* __restrict__ K,
    const float* __restrict__ nqw, const float* __restrict__ nkw,
    const float* __restrict__ cosT, const float* __restrict__ sinT)
{
    __shared__ float red[4];
    const size_t s = blockIdx.x;
    const int tid = threadIdx.x;

#pragma unroll
    for (int m = 0; m < 2; m++) {
        short* X = m ? K : Q;
        const float* w = m ? nkw : nqw;
        float v1[3], v2[3];
        float ss = 0.f;
#pragma unroll
        for (int j = 0; j < 3; j++) {
            const short2 p2 = *(const short2*)(X + s * D_ + 2 * (tid + 256 * j));
            v1[j] = bf2f(p2.x); v2[j] = bf2f(p2.y);
            ss += v1[j] * v1[j] + v2[j] * v2[j];
        }
        ss = block_sum_256(ss, red);
        const float rs = rsqrtf(ss * (1.f / D_) + EPS_);
#pragma unroll
        for (int j = 0; j < 3; j++) {
            const int p = tid + 256 * j;
            const int i = p & 63;
            const float c = cosT[s * 64 + i], sn = sinT[s * 64 + i];
            const float x1 = v1[j] * rs * w[2 * p];
            const float x2 = v2[j] * rs * w[2 * p + 1];
            short2 o;
            o.x = f2bf(x1 * c - x2 * sn);
            o.y = f2bf(x2 * c + x1 * sn);
            *(short2*)(X + s * D_ + 2 * p) = o;
        }
    }
}

// --------------------------- elementwise -----------------------------------
__global__ void add_kernel(const float* __restrict__ a, const float* __restrict__ b,
                           float* __restrict__ o, int n)
{
    const int i = blockIdx.x * 256 + threadIdx.x;
    if (i < n) o[i] = a[i] + b[i];
}

// ------------------------- VSA coarse path ---------------------------------
__global__ __launch_bounds__(128) void blockmean_bf16(const short* __restrict__ q,
                                                      float* __restrict__ qc)
{
    const int hb = blockIdx.x;
    const int h = hb >> 6, j = hb & 63;
    const int d = threadIdx.x;
    float sum = 0.f;
    for (int t = 0; t < 64; t++)
        sum += bf2f(q[(size_t)(j * 64 + t) * D_ + h * 128 + d]);
    qc[(size_t)hb * 128 + d] = sum * (1.f / 64.f);
}

__global__ __launch_bounds__(64) void coarse_kernel(
    const float* __restrict__ qc, const float* __restrict__ kc,
    const float* __restrict__ vc, float* __restrict__ oc, int* __restrict__ idxout)
{
    const int hb = blockIdx.x;
    const int h = hb >> 6, i = hb & 63;
    const int lane = threadIdx.x;
    __shared__ float p[64];

    const float* qv = qc + (size_t)hb * 128;
    const float* kv = kc + (size_t)((h << 6) + lane) * 128;
    float sc = 0.f;
    for (int d = 0; d < 128; d++) sc = fmaf(qv[d], kv[d], sc);
    sc *= SCALE_;

    float mx = sc;
#pragma unroll
    for (int off = 32; off > 0; off >>= 1) mx = fmaxf(mx, __shfl_xor(mx, off, 64));
    const float e = expf(sc - mx);
    float sumv = e;
#pragma unroll
    for (int off = 32; off > 0; off >>= 1) sumv += __shfl_xor(sumv, off, 64);
    const float pv = e / sumv;
    p[lane] = pv;
    __syncthreads();

    float o0 = 0.f, o1 = 0.f;
    for (int j = 0; j < 64; j++) {
        const float pj = p[j];
        const float* vr = vc + (size_t)((h << 6) + j) * 128;
        o0 = fmaf(pj, vr[lane], o0);
        o1 = fmaf(pj, vr[lane + 64], o1);
    }
    oc[(size_t)hb * 128 + lane]      = o0;
    oc[(size_t)hb * 128 + lane + 64] = o1;

    float v = pv;
    for (int t = 0; t < TOPK; t++) {
        float bv = v; int bi = lane;
#pragma unroll
        for (int off = 32; off > 0; off >>= 1) {
            const float ov = __shfl_xor(bv, off, 64);
            const int   oi = __shfl_xor(bi, off, 64);
            if (ov > bv || (ov == bv && oi < bi)) { bv = ov; bi = oi; }
        }
        if (lane == 0) idxout[hb * TOPK + t] = bi;
        if (lane == bi) v = -1.f;
    }
}

// ---------------------- MFMA flash attention -------------------------------
// MODE 0: fine VSA — Q,K,V bf16 (Qb,Kb,Vb), epilogue += oc*g.
// MODE 1: cross-attn — Q,K,V f32 (Q_, CK_, CV_).
template <int MODE>
__global__ __launch_bounds__(256) void attn_mfma(
    const short* __restrict__ Qb, const short* __restrict__ Kb,
    const short* __restrict__ Vbb,
    const float* __restrict__ Qf, const float* __restrict__ Kf,
    const float* __restrict__ Vff,
    const short* __restrict__ Gb, const float* __restrict__ ocp,
    const int* __restrict__ idxp, short* __restrict__ Ob)
{
    const int hb = blockIdx.x, h = hb >> 6, ib = hb & 63;
    const int tid = threadIdx.x, wid = tid >> 6, lane = tid & 63;
    const int g16 = lane >> 4, l15 = lane & 15;

    __shared__ __align__(16) short Ks[64 * 128];
    __shared__ __align__(16) short Vst[128 * 64];
    __shared__ __align__(16) short Ps[64 * 80];
    __shared__ int sel[8];
    if (tid < 8) sel[tid] = (MODE == 0) ? idxp[hb * 8 + tid] : tid;

    short8 qa[4];
    if (MODE == 0) {
        const short* qrow = Qb + (size_t)(ib * 64 + wid * 16 + l15) * D_ + h * 128;
#pragma unroll
        for (int kk = 0; kk < 4; kk++)
            qa[kk] = *(const short8*)(qrow + kk * 32 + g16 * 8);
    } else {
        const float* qrow = Qf + (size_t)(ib * 64 + wid * 16 + l15) * D_ + h * 128;
#pragma unroll
        for (int kk = 0; kk < 4; kk++) {
            const float4 f0 = *(const float4*)(qrow + kk * 32 + g16 * 8);
            const float4 f1 = *(const float4*)(qrow + kk * 32 + g16 * 8 + 4);
            short8 v;
            v[0] = f2bf(f0.x); v[1] = f2bf(f0.y); v[2] = f2bf(f0.z); v[3] = f2bf(f0.w);
            v[4] = f2bf(f1.x); v[5] = f2bf(f1.y); v[6] = f2bf(f1.z); v[7] = f2bf(f1.w);
            qa[kk] = v;
        }
    }

    f32x4 o[8];
#pragma unroll
    for (int n2 = 0; n2 < 8; n2++) o[n2] = (f32x4){0.f, 0.f, 0.f, 0.f};
    float mrow[4] = {-3e38f, -3e38f, -3e38f, -3e38f};
    float lrow[4] = {0.f, 0.f, 0.f, 0.f};
    __syncthreads();

    for (int t = 0; t < 8; t++) {
        const int jb = sel[t];
#pragma unroll
        for (int it = 0; it < 4; it++) {
            const int c = tid + 256 * it;
            const int key = c >> 4, u16 = c & 15;
            const int byte = (key * 256 + u16 * 16) ^ ((key & 7) << 4);
            if (MODE == 0) {
                *(short8*)((char*)Ks + byte) =
                    *(const short8*)(Kb + (size_t)(jb * 64 + key) * D_ + h * 128 + u16 * 8);
            } else {
                const float* src = Kf + (size_t)(jb * 64 + key) * D_ + h * 128 + u16 * 8;
                const float4 f0 = *(const float4*)src;
                const float4 f1 = *(const float4*)(src + 4);
                short8 v;
                v[0] = f2bf(f0.x); v[1] = f2bf(f0.y); v[2] = f2bf(f0.z); v[3] = f2bf(f0.w);
                v[4] = f2bf(f1.x); v[5] = f2bf(f1.y); v[6] = f2bf(f1.z); v[7] = f2bf(f1.w);
                *(short8*)((char*)Ks + byte) = v;
            }
        }
#pragma unroll
        for (int it = 0; it < 4; it++) {
            const int c = tid + 256 * it;
            const int key = c & 63, d8 = (c >> 6) * 8;
            float vv[8];
            if (MODE == 0) {
                const short8 v = *(const short8*)(Vbb + (size_t)(jb * 64 + key) * D_ + h * 128 + d8);
#pragma unroll
                for (int j = 0; j < 8; j++) vv[j] = bf2f(v[j]);
            } else {
                const float* src = Vff + (size_t)(jb * 64 + key) * D_ + h * 128 + d8;
                const float4 f0 = *(const float4*)src;
                const float4 f1 = *(const float4*)(src + 4);
                vv[0] = f0.x; vv[1] = f0.y; vv[2] = f0.z; vv[3] = f0.w;
                vv[4] = f1.x; vv[5] = f1.y; vv[6] = f1.z; vv[7] = f1.w;
            }
#pragma unroll
            for (int j = 0; j < 8; j++) {
                const int dim = d8 + j;
                const int byte = (dim * 128 + key * 2) ^ ((dim & 7) << 4);
                *(short*)((char*)Vst + byte) = f2bf(vv[j]);
            }
        }
        __syncthreads();

        f32x4 s[4];
#pragma unroll
        for (int nt = 0; nt < 4; nt++) {
            f32x4 acc = (f32x4){0.f, 0.f, 0.f, 0.f};
            const int key = nt * 16 + l15;
#pragma unroll
            for (int kk = 0; kk < 4; kk++) {
                const int byte = (key * 256 + (kk * 32 + g16 * 8) * 2) ^ ((key & 7) << 4);
                const short8 b = *(const short8*)((char*)Ks + byte);
                acc = __builtin_amdgcn_mfma_f32_16x16x32_bf16(qa[kk], b, acc, 0, 0, 0);
            }
            s[nt] = acc;
        }
#pragma unroll
        for (int nt = 0; nt < 4; nt++)
#pragma unroll
            for (int rr = 0; rr < 4; rr++) s[nt][rr] *= SCALE_;

        float alpha[4];
#pragma unroll
        for (int rr = 0; rr < 4; rr++) {
            float v = fmaxf(fmaxf(s[0][rr], s[1][rr]), fmaxf(s[2][rr], s[3][rr]));
            v = fmaxf(v, __shfl_xor(v, 1, 64));
            v = fmaxf(v, __shfl_xor(v, 2, 64));
            v = fmaxf(v, __shfl_xor(v, 4, 64));
            v = fmaxf(v, __shfl_xor(v, 8, 64));
            const float mn = fmaxf(mrow[rr], v);
            alpha[rr] = expf(mrow[rr] - mn);
            mrow[rr] = mn;
        }
        float rs[4] = {0.f, 0.f, 0.f, 0.f};
#pragma unroll
        for (int nt = 0; nt < 4; nt++)
#pragma unroll
            for (int rr = 0; rr < 4; rr++) {
                const float p = expf(s[nt][rr] - mrow[rr]);
                s[nt][rr] = p;
                rs[rr] += p;
            }
#pragma unroll
        for (int rr = 0; rr < 4; rr++) {
            float v = rs[rr];
            v += __shfl_xor(v, 1, 64);
            v += __shfl_xor(v, 2, 64);
            v += __shfl_xor(v, 4, 64);
            v += __shfl_xor(v, 8, 64);
            lrow[rr] = lrow[rr] * alpha[rr] + v;
        }
#pragma unroll
        for (int n2 = 0; n2 < 8; n2++)
#pragma unroll
            for (int rr = 0; rr < 4; rr++) o[n2][rr] *= alpha[rr];

#pragma unroll
        for (int nt = 0; nt < 4; nt++)
#pragma unroll
            for (int rr = 0; rr < 4; rr++)
                Ps[(wid * 16 + g16 * 4 + rr) * 80 + nt * 16 + l15] = f2bf(s[nt][rr]);

#pragma unroll
        for (int kk2 = 0; kk2 < 2; kk2++) {
            const short8 pa = *(const short8*)(Ps + (wid * 16 + l15) * 80 + kk2 * 32 + g16 * 8);
#pragma unroll
            for (int n2 = 0; n2 < 8; n2++) {
                const int dim = n2 * 16 + l15;
                const int byte = (dim * 128 + (kk2 * 32 + g16 * 8) * 2) ^ ((dim & 7) << 4);
                const short8 vb = *(const short8*)((char*)Vst + byte);
                o[n2] = __builtin_amdgcn_mfma_f32_16x16x32_bf16(pa, vb, o[n2], 0, 0, 0);
            }
        }
        __syncthreads();
    }

#pragma unroll
    for (int n2 = 0; n2 < 8; n2++) {
        const int col = n2 * 16 + l15;
        const float ocv = (MODE == 0) ? ocp[(size_t)hb * 128 + col] : 0.f;
#pragma unroll
        for (int rr = 0; rr < 4; rr++) {
            const int row = ib * 64 + wid * 16 + g16 * 4 + rr;
            float val = o[n2][rr] / lrow[rr];
            if (MODE == 0)
                val += ocv * bf2f(Gb[(size_t)row * D_ + h * 128 + col]);
            Ob[(size_t)row * D_ + h * 128 + col] = f2bf(val);
        }
    }
}

// ---------------------------------------------------------------------------
extern "C" void kernel_launch(void* const* d_in, const int* in_sizes, int n_in,
                              void* d_out, int out_size, void* d_ws, size_t ws_size,
                              hipStream_t stream)
{
    const float* h_in = (const float*)d_in[0];
    const float* enc  = (const float*)d_in[1];
    const float* temb = (const float*)d_in[2];
    const float* cosT = (const float*)d_in[3];
    const float* sinT = (const float*)d_in[4];
    const float* sst  = (const float*)d_in[5];
    const float* Wq = (const float*)d_in[6];   const float* bq = (const float*)d_in[7];
    const float* Wk = (const float*)d_in[8];   const float* bk = (const float*)d_in[9];
    const float* Wv = (const float*)d_in[10];  const float* bv = (const float*)d_in[11];
    const float* Wg = (const float*)d_in[12];  const float* bg = (const float*)d_in[13];
    const float* Wo = (const float*)d_in[14];  const float* bo = (const float*)d_in[15];
    const float* nq_w  = (const float*)d_in[16];
    const float* nk_w  = (const float*)d_in[17];
    const float* ln1_w = (const float*)d_in[18];
    const float* ln1_b = (const float*)d_in[19];
    const float* cWq = (const float*)d_in[20]; const float* cbq = (const float*)d_in[21];
    const float* cWk = (const float*)d_in[22]; const float* cbk = (const float*)d_in[23];
    const float* cWv = (const float*)d_in[24]; const float* cbv = (const float*)d_in[25];
    const float* cWo = (const float*)d_in[26]; const float* cbo = (const float*)d_in[27];
    const float* cnq_w = (const float*)d_in[28];
    const float* cnk_w = (const float*)d_in[29];
    const float* W1 = (const float*)d_in[30];  const float* b1 = (const float*)d_in[31];
    const float* W2 = (const float*)d_in[32];  const float* b2 = (const float*)d_in[33];
    float* out = (float*)d_out;

    char* base = (char*)d_ws;
    size_t off = 0;
    auto alloc = [&](size_t bytes) {
        char* p = base + off;
        off += (bytes + 255) & ~(size_t)255;
        return p;
    };
    const size_t SD = (size_t)S_ * D_;
    float* e_   = (float*)alloc(6 * D_ * 4);
    float* Q_   = (float*)alloc(SD * 4);       // cq (cross path)
    float* K_   = (float*)alloc(SD * 4);       // resid1/resid2
    float* CK_  = (float*)alloc((size_t)L_ * D_ * 4);
    float* CV_  = (float*)alloc((size_t)L_ * D_ * 4);
    float* qc_  = (float*)alloc((size_t)H_ * 64 * 128 * 4);
    float* kc_  = (float*)alloc((size_t)H_ * 64 * 128 * 4);
    float* vc_  = (float*)alloc((size_t)H_ * 64 * 128 * 4);
    float* oc_  = (float*)alloc((size_t)H_ * 64 * 128 * 4);
    int*   idx_ = (int*)alloc((size_t)H_ * 64 * TOPK * 4);
    short* Nb   = (short*)alloc(SD * 2);       // live during W1 (norm3)
    // ---- FFC alias region: QKVGb .. Wgt (~83 MB, all dead by FFN) ----
    short* QKVGb = (short*)alloc(4 * SD * 2);  // q|k|v|g bf16, seg stride SD
    short* attn_b = (short*)alloc(SD * 2);
    short* enc_b  = (short*)alloc((size_t)L_ * D_ * 2);
    const size_t WDD = (size_t)D_ * D_;
    short* Wqt = (short*)alloc(WDD * 2);       // Wqt,Wkt,Wvt,Wgt contiguous
    short* Wkt = (short*)alloc(WDD * 2);
    short* Wvt = (short*)alloc(WDD * 2);
    short* Wgt = (short*)alloc(WDD * 2);
    // ---- end alias region ----
    short* Wot = (short*)alloc(WDD * 2);
    short* cWqt = (short*)alloc(WDD * 2); short* cWkt = (short*)alloc(WDD * 2);
    short* cWvt = (short*)alloc(WDD * 2); short* cWot = (short*)alloc(WDD * 2);
    short* W1t = (short*)alloc((size_t)D_ * FF_ * 2);
    short* W2t = (short*)alloc((size_t)D_ * FF_ * 2);
    float* bcat = (float*)alloc(6144 * 4);
    short* FFC = QKVGb;   // S x FF bf16 (73.4 MB) over dead region (~83 MB)
    short* Qb = QKVGb;
    short* Kb = QKVGb + SD;
    short* Vb = QKVGb + 2 * SD;
    short* Gb = QKVGb + 3 * SD;

    const dim3 b256(256);
    const dim3 gDD(D_ / 64, D_ / 64);
    const dim3 gN1536(D_ / 64, S_ / 128);      // 24 x 32 = 768 blocks

    add_kernel<<<dim3((6 * D_ + 255) / 256), b256, 0, stream>>>(sst, temb, e_, 6 * D_);
    ln_bf16<1><<<dim3(S_), b256, 0, stream>>>(h_in, Nb, e_ + D_, e_);
    fill_bcat<<<dim3(24), b256, 0, stream>>>(bq, bk, bv, bg, bcat);

    transpose_w<<<gDD, b256, 0, stream>>>(Wq, Wqt, D_, D_);
    transpose_w<<<gDD, b256, 0, stream>>>(Wk, Wkt, D_, D_);
    transpose_w<<<gDD, b256, 0, stream>>>(Wv, Wvt, D_, D_);
    transpose_w<<<gDD, b256, 0, stream>>>(Wg, Wgt, D_, D_);
    transpose_w<<<gDD, b256, 0, stream>>>(Wo, Wot, D_, D_);
    transpose_w<<<gDD, b256, 0, stream>>>(cWq, cWqt, D_, D_);
    transpose_w<<<gDD, b256, 0, stream>>>(cWk, cWkt, D_, D_);
    transpose_w<<<gDD, b256, 0, stream>>>(cWv, cWvt, D_, D_);
    transpose_w<<<gDD, b256, 0, stream>>>(cWo, cWot, D_, D_);
    transpose_w<<<dim3(FF_ / 64, D_ / 64), b256, 0, stream>>>(W1, W1t, D_, FF_);
    transpose_w<<<dim3(D_ / 64, FF_ / 64), b256, 0, stream>>>(W2, W2t, FF_, D_);
    cvt_bf16_kernel<<<dim3((L_ * D_ / 4 + 255) / 256), b256, 0, stream>>>(enc, enc_b, L_ * D_ / 4);

    // fused QKVG projection -> QKVGb (all bf16)
    gemm17<4><<<dim3(6144 / 64, S_ / 128), b256, 0, stream>>>(
        Nb, Wqt, bcat, nullptr, QKVGb, S_, 6144, D_, nullptr, nullptr);

    // fused rms + rope for q,k (bf16 in-place)
    rmsrope_qk_bf16<<<dim3(S_), b256, 0, stream>>>(Qb, Kb, nq_w, nk_w, cosT, sinT);

    blockmean_bf16<<<dim3(H_ * 64), dim3(128), 0, stream>>>(Qb, qc_);
    blockmean_bf16<<<dim3(H_ * 64), dim3(128), 0, stream>>>(Kb, kc_);
    blockmean_bf16<<<dim3(H_ * 64), dim3(128), 0, stream>>>(Vb, vc_);
    coarse_kernel<<<dim3(H_ * 64), dim3(64), 0, stream>>>(qc_, kc_, vc_, oc_, idx_);

    attn_mfma<0><<<dim3(H_ * 64), b256, 0, stream>>>(
        Qb, Kb, Vb, nullptr, nullptr, nullptr, Gb, oc_, idx_, attn_b);

    // Wo fused with resid-gate: K_ = h_in + (attn@Wo + bo) * gate
    gemm17<6><<<gN1536, b256, 0, stream>>>(attn_b, Wot, bo, K_, nullptr, S_, D_, D_,
                                           h_in, e_ + 2 * D_);

    ln_bf16<0><<<dim3(S_), b256, 0, stream>>>(K_, Nb, ln1_w, ln1_b);
    gemm17<0><<<gN1536, b256, 0, stream>>>(Nb, cWqt, cbq, Q_, nullptr, S_, D_, D_,
                                           nullptr, nullptr);
    rms_kernel<<<dim3(S_), b256, 0, stream>>>(Q_, cnq_w);

    const dim3 gLenc(D_ / 64, L_ / 128);
    gemm17<0><<<gLenc, b256, 0, stream>>>(enc_b, cWkt, cbk, CK_, nullptr, L_, D_, D_,
                                          nullptr, nullptr);
    rms_kernel<<<dim3(L_), b256, 0, stream>>>(CK_, cnk_w);
    gemm17<0><<<gLenc, b256, 0, stream>>>(enc_b, cWvt, cbv, CV_, nullptr, L_, D_, D_,
                                          nullptr, nullptr);

    attn_mfma<1><<<dim3(H_ * 64), b256, 0, stream>>>(
        nullptr, nullptr, nullptr, Q_, CK_, CV_, nullptr, nullptr, nullptr, attn_b);

    // cWo fused with residual: K_ += cout@cWo + cbo
    gemm17<7><<<gN1536, b256, 0, stream>>>(attn_b, cWot, cbo, K_, nullptr, S_, D_, D_,
                                           nullptr, nullptr);

    // norm3 -> Nb ; FFN: W1(gelu->FFC bf16) ; W2 fused with final resid-gate
    ln_bf16<1><<<dim3(S_), b256, 0, stream>>>(K_, Nb, e_ + 4 * D_, e_ + 3 * D_);
    gemm17<2><<<dim3(FF_ / 64, S_ / 128), b256, 0, stream>>>(
        Nb, W1t, b1, nullptr, FFC, S_, FF_, D_, nullptr, nullptr);
    gemm17<6><<<gN1536, b256, 0, stream>>>(FFC, W2t, b2, out, nullptr, S_, D_, FF_,
                                           K_, e_ + 5 * D_);
}